// Round 7
// baseline (490.890 us; speedup 1.0000x reference)
//
#include <hip/hip_runtime.h>

// NeRF fused render, MI355X. 16384 rays x 64 samples, MLP 3->256->256->256->4.
// R6 resubmit (never ran - broker timeout). R4 structure + explicit AGPR pinning
// of h-state (r5 spilled it: 856MB WRITE_SIZE scratch traffic, 100% of runtime).
// 1 wave = 1 ray (64 samples = 2 sample-tiles); block = 4 waves; grid 4096.
// hf[2][16]+hg[2][16] = 256 regs = the AGPR half of the unified file, pinned via
// empty asm "+a" at each production site; gfx950 MFMA reads A/B straight from
// AGPR. Weights async-staged (global_load_lds) into 2x16KB LDS double buffer;
// 17-tile chain W2 x8 -> W3 x8 -> W4; each weight ds_read_b128 feeds 2 MFMAs
// (64 FLOP/B). Repack via cvt_pk_bf16 + permlane32_swap (r2/r3/r5 validated
// numerics, absmax 7.9e-4).

#define HID 256

typedef short bf16x8 __attribute__((ext_vector_type(8)));
typedef float f32x4  __attribute__((ext_vector_type(4)));
typedef float f32x16 __attribute__((ext_vector_type(16)));
typedef int   i32x4  __attribute__((ext_vector_type(4)));
typedef int   i32x2v __attribute__((ext_vector_type(2)));

// Pin a 128-bit fragment into the AGPR register class.
#define PIN_A(x) asm("" : "+a"(x))

static __device__ __forceinline__ unsigned short f2bf(float f) {
    unsigned u = __float_as_uint(f);
    u += 0x7fffu + ((u >> 16) & 1u);   // RNE
    return (unsigned short)(u >> 16);
}

// Fragment order (validated r2/r3/r5): [nt][kt 16][lane 64][e 8],
// element = W[k = kt*16 + 8*(lane>>5) + e][n = nt*32 + (lane&31)].
__global__ void prep_pack(const float* __restrict__ W2, const float* __restrict__ W3,
                          const float* __restrict__ W4,
                          unsigned short* __restrict__ W2p, unsigned short* __restrict__ W3p,
                          unsigned short* __restrict__ W4p) {
    int t = blockIdx.x * 256 + threadIdx.x;
    if (t < 65536) {
        int e  = t & 7;
        int l  = (t >> 3) & 63;
        int kt = (t >> 9) & 15;
        int nt = t >> 13;
        int k = kt * 16 + 8 * (l >> 5) + e;
        int n = nt * 32 + (l & 31);
        W2p[t] = f2bf(W2[k * HID + n]);
        W3p[t] = f2bf(W3[k * HID + n]);
    } else if (t < 65536 + 8192) {
        int u  = t - 65536;
        int e  = u & 7;
        int l  = (u >> 3) & 63;
        int kt = u >> 9;
        int k = kt * 16 + 8 * (l >> 5) + e;
        int n = l & 31;                        // cols 0..3 real, 4..31 zero pad
        W4p[u] = f2bf((n < 4) ? W4[k * 4 + n] : 0.0f);
    }
}

static __device__ __forceinline__ float decode_scalar(const unsigned* __restrict__ p) {
    unsigned w0 = p[0];
    if (w0 == 0u) {
        unsigned w1 = p[1];
        if (w1 != 0u) return (float)__hiloint2double((int)w1, (int)w0);
        return 0.0f;
    }
    if (w0 < 0x00800000u) return (float)(int)w0;   // small int
    return __uint_as_float(w0);                    // float32 bits
}

static __device__ __forceinline__ unsigned cvt_pk_bf16(float lo, float hi) {
    unsigned r;
    asm("v_cvt_pk_bf16_f32 %0, %1, %2" : "=v"(r) : "v"(lo), "v"(hi));
    return r;
}

static __device__ __forceinline__ void gload_lds16(const char* g, char* l) {
    __builtin_amdgcn_global_load_lds(
        (const __attribute__((address_space(1))) void*)g,
        (__attribute__((address_space(3))) void*)l, 16, 0, 0);
}

// One 256->256 layer. Per st: issue async loads of next chain tile into the idle
// buffer, 16 weight ds_read_b128 each feeding 2 MFMAs (one per sample tile),
// bias+relu+cvt_pk+permlane repack into o[t][2st], o[t][2st+1] (AGPR-pinned),
// one barrier.
template<int BASE>
static __device__ __forceinline__ void dense_layer(
    i32x4 (&h)[2][16], i32x4 (&o)[2][16], char* __restrict__ wlds,
    const char* __restrict__ W2p, const char* __restrict__ W3p,
    const char* __restrict__ W4p, const float* __restrict__ bias,
    int tid, int l, int hi)
{
#pragma unroll
    for (int st = 0; st < 8; ++st) {
        const int gi = BASE + st;                       // global chain index 0..15
        char* live = wlds + (gi & 1) * 16384;
        char* idle = wlds + ((gi + 1) & 1) * 16384;
        const int ni = gi + 1;                          // next tile: W2 x8, W3 x8, W4
        const char* nsrc = (ni < 8) ? (W2p + ni * 16384)
                         : (ni < 16 ? (W3p + (ni - 8) * 16384) : W4p);
#pragma unroll
        for (int j = 0; j < 4; ++j)
            gload_lds16(nsrc + j * 4096 + tid * 16, idle + j * 4096 + tid * 16);

        f32x16 a0 = {}, a1 = {};
#pragma unroll
        for (int kk = 0; kk < 16; ++kk) {
            bf16x8 wv = *(const bf16x8*)(live + kk * 1024 + l * 16);
            a0 = __builtin_amdgcn_mfma_f32_32x32x16_bf16(wv, (bf16x8&)h[0][kk], a0, 0, 0, 0);
            a1 = __builtin_amdgcn_mfma_f32_32x32x16_bf16(wv, (bf16x8&)h[1][kk], a1, 0, 0, 0);
        }
        // D layout (HW-verified m74/m101 + r2/r3/r5 pass): col = lane&31 = sample,
        // row n_local(r) = (r&3) + 8*(r>>2) + 4*hi.  Bias uniform over t: hoist.
        f32x4 bb[4];
#pragma unroll
        for (int q = 0; q < 4; ++q)
            bb[q] = *(const f32x4*)(bias + st * 32 + 8 * q + 4 * hi);
#pragma unroll
        for (int t = 0; t < 2; ++t) {
            unsigned qw[4][2];
#pragma unroll
            for (int q = 0; q < 4; ++q) {
                float v0 = fmaxf((t ? a1 : a0)[4*q+0] + bb[q][0], 0.0f);
                float v1 = fmaxf((t ? a1 : a0)[4*q+1] + bb[q][1], 0.0f);
                float v2 = fmaxf((t ? a1 : a0)[4*q+2] + bb[q][2], 0.0f);
                float v3 = fmaxf((t ? a1 : a0)[4*q+3] + bb[q][3], 0.0f);
                qw[q][0] = cvt_pk_bf16(v0, v1);
                qw[q][1] = cvt_pk_bf16(v2, v3);
            }
            // permlane32_swap: r0 = {a.lo32, b.lo32}, r1 = {a.hi32, b.hi32}.
#pragma unroll
            for (int j = 0; j < 2; ++j) {
                i32x2v r = __builtin_amdgcn_permlane32_swap((int)qw[0][j], (int)qw[1][j], false, false);
                i32x2v s = __builtin_amdgcn_permlane32_swap((int)qw[2][j], (int)qw[3][j], false, false);
                o[t][2*st  ][j]     = r[0];
                o[t][2*st  ][j + 2] = r[1];
                o[t][2*st+1][j]     = s[0];
                o[t][2*st+1][j + 2] = s[1];
            }
            PIN_A(o[t][2*st  ]);     // park the finished frags in AGPR
            PIN_A(o[t][2*st+1]);
        }
        __syncthreads();   // live fully consumed by all waves; idle loads drained
    }
}

__launch_bounds__(256, 2)
__global__ void nerf_fused(
    const float* __restrict__ origins, const float* __restrict__ dirs,
    const float* __restrict__ W1, const float* __restrict__ b1,
    const float* __restrict__ b2, const float* __restrict__ b3,
    const float* __restrict__ b4,
    const unsigned* __restrict__ nearp, const unsigned* __restrict__ farp,
    const unsigned short* __restrict__ W2p_, const unsigned short* __restrict__ W3p_,
    const unsigned short* __restrict__ W4p_,
    float* __restrict__ out)
{
    __shared__ char wlds[32768];                // 2 x 16KB weight double-buffer
    const int tid  = threadIdx.x;
    const int w    = tid >> 6;                  // wave = ray-in-block
    const int l    = tid & 63;
    const int hi   = l >> 5;
    const long ray = (long)blockIdx.x * 4 + w;
    const char* W2p = (const char*)W2p_;
    const char* W3p = (const char*)W3p_;
    const char* W4p = (const char*)W4p_;

    const float nearv = decode_scalar(nearp);
    const float farv  = decode_scalar(farp);
    const float delta = (farv - nearv) * (1.0f / 64.0f);

    // prologue: async-stage W2 tile0 -> buf0 (latency hides under layer 1)
#pragma unroll
    for (int j = 0; j < 4; ++j)
        gload_lds16(W2p + j * 4096 + tid * 16, wlds + j * 4096 + tid * 16);

    // ---- layer 1: h1 = relu((o@W1+b1) + z*(d@W1)); fp32, packed straight to regs.
    // owdw scratch in buf1 (wave slice; consumed before st0's async loads hit buf1).
    float* owdw = (float*)(wlds + 16384) + w * 512;
    {
        float o0 = origins[ray*3+0], o1 = origins[ray*3+1], o2 = origins[ray*3+2];
        float d0 = dirs[ray*3+0],    d1 = dirs[ray*3+1],    d2 = dirs[ray*3+2];
        int n0 = l * 4;
        f32x4 wa = *(const f32x4*)(W1 + n0);
        f32x4 wb = *(const f32x4*)(W1 + 256 + n0);
        f32x4 wc = *(const f32x4*)(W1 + 512 + n0);
        f32x4 bbv = *(const f32x4*)(b1 + n0);
        f32x4 ow, dw;
#pragma unroll
        for (int e = 0; e < 4; ++e) {
            ow[e] = fmaf(o2, wc[e], fmaf(o1, wb[e], fmaf(o0, wa[e], bbv[e])));
            dw[e] = fmaf(d2, wc[e], fmaf(d1, wb[e], d0 * wa[e]));
        }
        *(f32x4*)(owdw + n0) = ow;
        *(f32x4*)(owdw + 256 + n0) = dw;
    }
    i32x4 hf[2][16], hg[2][16];
    {
        float s0 = (float)(l & 31);
        float z0 = nearv + (farv - nearv) * (s0 + 0.5f)  * 0.015625f;
        float z1 = nearv + (farv - nearv) * (s0 + 32.5f) * 0.015625f;
#pragma unroll
        for (int kt = 0; kt < 16; ++kt) {
            int k0 = kt * 16 + 8 * hi;
            f32x4 oa = *(const f32x4*)(owdw + k0);
            f32x4 ob = *(const f32x4*)(owdw + k0 + 4);
            f32x4 da = *(const f32x4*)(owdw + 256 + k0);
            f32x4 db = *(const f32x4*)(owdw + 256 + k0 + 4);
#pragma unroll
            for (int t = 0; t < 2; ++t) {
                float z = t ? z1 : z0;
                i32x4 pk;
                pk[0] = (int)cvt_pk_bf16(fmaxf(fmaf(z,da[0],oa[0]),0.f), fmaxf(fmaf(z,da[1],oa[1]),0.f));
                pk[1] = (int)cvt_pk_bf16(fmaxf(fmaf(z,da[2],oa[2]),0.f), fmaxf(fmaf(z,da[3],oa[3]),0.f));
                pk[2] = (int)cvt_pk_bf16(fmaxf(fmaf(z,db[0],ob[0]),0.f), fmaxf(fmaf(z,db[1],ob[1]),0.f));
                pk[3] = (int)cvt_pk_bf16(fmaxf(fmaf(z,db[2],ob[2]),0.f), fmaxf(fmaf(z,db[3],ob[3]),0.f));
                hf[t][kt] = pk;
                PIN_A(hf[t][kt]);          // park layer-1 h in AGPR
            }
        }
    }
    __syncthreads();   // buf0 staged (vmcnt drained by barrier); owdw consumed

    // ---- layers 2, 3 (17-tile async chain: W2 x8 -> W3 x8 -> W4) ----
    dense_layer<0>(hf, hg, wlds, W2p, W3p, W4p, b2, tid, l, hi);
    dense_layer<8>(hg, hf, wlds, W2p, W3p, W4p, b3, tid, l, hi);
    // W4 fragments now in buf0 (gi=16 even)

    // ---- layer 4: 256 -> 4 (padded to 32 rows) + sigmoid/alpha ----
    float* comp = (float*)(wlds + 16384);       // buf1 dead after last barrier
    {
        f32x16 a0 = {}, a1 = {};
#pragma unroll
        for (int kk = 0; kk < 16; ++kk) {
            bf16x8 wv = *(const bf16x8*)(wlds + kk * 1024 + l * 16);
            a0 = __builtin_amdgcn_mfma_f32_32x32x16_bf16(wv, (bf16x8&)hf[0][kk], a0, 0, 0, 0);
            a1 = __builtin_amdgcn_mfma_f32_32x32x16_bf16(wv, (bf16x8&)hf[1][kk], a1, 0, 0, 0);
        }
        // rows 0..3 (r,g,b,sigma) live in regs 0..3 of hi=0 lanes; col = sample&31
        if (l < 32) {
            float bb0 = b4[0], bb1 = b4[1], bb2 = b4[2], bb3 = b4[3];
#pragma unroll
            for (int t = 0; t < 2; ++t) {
                float rr = (t ? a1 : a0)[0] + bb0;
                float gg = (t ? a1 : a0)[1] + bb1;
                float bl = (t ? a1 : a0)[2] + bb2;
                float sg = (t ? a1 : a0)[3] + bb3;
                float alpha = 1.0f - __expf(-fmaxf(sg, 0.0f) * delta);
                f32x4 cv;
                cv[0] = 1.0f / (1.0f + __expf(-rr));
                cv[1] = 1.0f / (1.0f + __expf(-gg));
                cv[2] = 1.0f / (1.0f + __expf(-bl));
                cv[3] = alpha;
                *(f32x4*)(comp + (w * 64 + t * 32 + l) * 4) = cv;   // wave-private
            }
        }
        asm volatile("s_waitcnt lgkmcnt(0)" ::: "memory");  // same-wave write->read
    }

    // ---- composite: each wave scans its own ray; sample = lane ----
    {
        f32x4 cv = *(const f32x4*)(comp + (w * 64 + l) * 4);
        float alpha = cv[3];
        float p = 1.0f - alpha + 1e-10f;
        float P = p;                         // inclusive cumprod across 64 lanes
#pragma unroll
        for (int d = 1; d < 64; d <<= 1) {
            float u = __shfl_up(P, d, 64);
            if (l >= d) P *= u;
        }
        float T = __shfl_up(P, 1, 64);       // exclusive
        if (l == 0) T = 1.0f;
        float wt = alpha * T;
        float cr = wt * cv[0], cg = wt * cv[1], cb = wt * cv[2];
#pragma unroll
        for (int d = 32; d >= 1; d >>= 1) {
            cr += __shfl_down(cr, d, 64);
            cg += __shfl_down(cg, d, 64);
            cb += __shfl_down(cb, d, 64);
        }
        if (l == 0) {
            out[ray * 3 + 0] = cr;
            out[ray * 3 + 1] = cg;
            out[ray * 3 + 2] = cb;
        }
    }
}

extern "C" void kernel_launch(void* const* d_in, const int* in_sizes, int n_in,
                              void* d_out, int out_size, void* d_ws, size_t ws_size,
                              hipStream_t stream) {
    const float* origins = (const float*)d_in[0];
    const float* dirs    = (const float*)d_in[1];
    const float* W1 = (const float*)d_in[2];
    const float* b1 = (const float*)d_in[3];
    const float* W2 = (const float*)d_in[4];
    const float* b2 = (const float*)d_in[5];
    const float* W3 = (const float*)d_in[6];
    const float* b3 = (const float*)d_in[7];
    const float* W4 = (const float*)d_in[8];
    const float* b4 = (const float*)d_in[9];
    const unsigned* nearp = (const unsigned*)d_in[10];
    const unsigned* farp  = (const unsigned*)d_in[11];
    float* out = (float*)d_out;

    unsigned short* W2p = (unsigned short*)d_ws;          // 128KB
    unsigned short* W3p = W2p + 65536;                    // 128KB
    unsigned short* W4p = W2p + 131072;                   // 16KB

    prep_pack<<<288, 256, 0, stream>>>(W2, W3, W4, W2p, W3p, W4p);
    nerf_fused<<<4096, 256, 0, stream>>>(origins, dirs, W1, b1, b2, b3, b4,
                                         nearp, farp, W2p, W3p, W4p, out);
}

// Round 12
// 415.416 us; speedup vs baseline: 1.1817x; 1.1817x over previous
//
#include <hip/hip_runtime.h>

// NeRF fused render, MI355X. 16384 rays x 64 samples, MLP 3->256->256->256->4.
// R8 fourth submit (3x broker timeout + 1x container fail; never run).
// R6 structure + __launch_bounds__(256,1). R7 evidence: (256,2) caps waves at
// 256 unified regs (512 phys/SIMD / 2) -> 128 VGPR + 128 AGPR allocated, rest
// of the 256-reg h-state spilled (819MB WRITE_SIZE = whole 490us runtime).
// At (256,1): budget 512/wave; 256 AGPR (hf+hg pinned via asm "+a") + ~160
// VGPR fits, no spill. 1 wave = 1 ray (64 samples = 2 sample-tiles); block =
// 4 waves; grid 4096. Weights async-staged (global_load_lds) into 2x16KB LDS
// double buffer; 17-tile chain W2 x8 -> W3 x8 -> W4; each weight ds_read_b128
// feeds 2 MFMAs (64 FLOP/B). LDS-pipe floor ~87us; MFMA floor ~31us.
// LDS-bound by design; 16 independent kk chains/wave overlap ds_read w/ MFMA.

#define HID 256

typedef short bf16x8 __attribute__((ext_vector_type(8)));
typedef float f32x4  __attribute__((ext_vector_type(4)));
typedef float f32x16 __attribute__((ext_vector_type(16)));
typedef int   i32x4  __attribute__((ext_vector_type(4)));
typedef int   i32x2v __attribute__((ext_vector_type(2)));

// Pin a 128-bit fragment into the AGPR register class.
#define PIN_A(x) asm("" : "+a"(x))

static __device__ __forceinline__ unsigned short f2bf(float f) {
    unsigned u = __float_as_uint(f);
    u += 0x7fffu + ((u >> 16) & 1u);   // RNE
    return (unsigned short)(u >> 16);
}

// Fragment order (validated r2/r3/r5/r7): [nt][kt 16][lane 64][e 8],
// element = W[k = kt*16 + 8*(lane>>5) + e][n = nt*32 + (lane&31)].
__global__ void prep_pack(const float* __restrict__ W2, const float* __restrict__ W3,
                          const float* __restrict__ W4,
                          unsigned short* __restrict__ W2p, unsigned short* __restrict__ W3p,
                          unsigned short* __restrict__ W4p) {
    int t = blockIdx.x * 256 + threadIdx.x;
    if (t < 65536) {
        int e  = t & 7;
        int l  = (t >> 3) & 63;
        int kt = (t >> 9) & 15;
        int nt = t >> 13;
        int k = kt * 16 + 8 * (l >> 5) + e;
        int n = nt * 32 + (l & 31);
        W2p[t] = f2bf(W2[k * HID + n]);
        W3p[t] = f2bf(W3[k * HID + n]);
    } else if (t < 65536 + 8192) {
        int u  = t - 65536;
        int e  = u & 7;
        int l  = (u >> 3) & 63;
        int kt = u >> 9;
        int k = kt * 16 + 8 * (l >> 5) + e;
        int n = l & 31;                        // cols 0..3 real, 4..31 zero pad
        W4p[u] = f2bf((n < 4) ? W4[k * 4 + n] : 0.0f);
    }
}

static __device__ __forceinline__ float decode_scalar(const unsigned* __restrict__ p) {
    unsigned w0 = p[0];
    if (w0 == 0u) {
        unsigned w1 = p[1];
        if (w1 != 0u) return (float)__hiloint2double((int)w1, (int)w0);
        return 0.0f;
    }
    if (w0 < 0x00800000u) return (float)(int)w0;   // small int
    return __uint_as_float(w0);                    // float32 bits
}

static __device__ __forceinline__ unsigned cvt_pk_bf16(float lo, float hi) {
    unsigned r;
    asm("v_cvt_pk_bf16_f32 %0, %1, %2" : "=v"(r) : "v"(lo), "v"(hi));
    return r;
}

static __device__ __forceinline__ void gload_lds16(const char* g, char* l) {
    __builtin_amdgcn_global_load_lds(
        (const __attribute__((address_space(1))) void*)g,
        (__attribute__((address_space(3))) void*)l, 16, 0, 0);
}

// One 256->256 layer. Per st: issue async loads of next chain tile into the idle
// buffer, 16 weight ds_read_b128 each feeding 2 MFMAs (one per sample tile),
// bias+relu+cvt_pk+permlane repack into o[t][2st], o[t][2st+1] (AGPR-pinned),
// one barrier.
template<int BASE>
static __device__ __forceinline__ void dense_layer(
    i32x4 (&h)[2][16], i32x4 (&o)[2][16], char* __restrict__ wlds,
    const char* __restrict__ W2p, const char* __restrict__ W3p,
    const char* __restrict__ W4p, const float* __restrict__ bias,
    int tid, int l, int hi)
{
#pragma unroll
    for (int st = 0; st < 8; ++st) {
        const int gi = BASE + st;                       // global chain index 0..15
        char* live = wlds + (gi & 1) * 16384;
        char* idle = wlds + ((gi + 1) & 1) * 16384;
        const int ni = gi + 1;                          // next tile: W2 x8, W3 x8, W4
        const char* nsrc = (ni < 8) ? (W2p + ni * 16384)
                         : (ni < 16 ? (W3p + (ni - 8) * 16384) : W4p);
#pragma unroll
        for (int j = 0; j < 4; ++j)
            gload_lds16(nsrc + j * 4096 + tid * 16, idle + j * 4096 + tid * 16);

        f32x16 a0 = {}, a1 = {};
#pragma unroll
        for (int kk = 0; kk < 16; ++kk) {
            bf16x8 wv = *(const bf16x8*)(live + kk * 1024 + l * 16);
            a0 = __builtin_amdgcn_mfma_f32_32x32x16_bf16(wv, (bf16x8&)h[0][kk], a0, 0, 0, 0);
            a1 = __builtin_amdgcn_mfma_f32_32x32x16_bf16(wv, (bf16x8&)h[1][kk], a1, 0, 0, 0);
        }
        // D layout (HW-verified m74/m101 + r2/r3/r5/r7 pass): col = lane&31 = sample,
        // row n_local(r) = (r&3) + 8*(r>>2) + 4*hi.  Bias uniform over t: hoist.
        f32x4 bb[4];
#pragma unroll
        for (int q = 0; q < 4; ++q)
            bb[q] = *(const f32x4*)(bias + st * 32 + 8 * q + 4 * hi);
#pragma unroll
        for (int t = 0; t < 2; ++t) {
            unsigned qw[4][2];
#pragma unroll
            for (int q = 0; q < 4; ++q) {
                float v0 = fmaxf((t ? a1 : a0)[4*q+0] + bb[q][0], 0.0f);
                float v1 = fmaxf((t ? a1 : a0)[4*q+1] + bb[q][1], 0.0f);
                float v2 = fmaxf((t ? a1 : a0)[4*q+2] + bb[q][2], 0.0f);
                float v3 = fmaxf((t ? a1 : a0)[4*q+3] + bb[q][3], 0.0f);
                qw[q][0] = cvt_pk_bf16(v0, v1);
                qw[q][1] = cvt_pk_bf16(v2, v3);
            }
            // permlane32_swap: r0 = {a.lo32, b.lo32}, r1 = {a.hi32, b.hi32}.
#pragma unroll
            for (int j = 0; j < 2; ++j) {
                i32x2v r = __builtin_amdgcn_permlane32_swap((int)qw[0][j], (int)qw[1][j], false, false);
                i32x2v s = __builtin_amdgcn_permlane32_swap((int)qw[2][j], (int)qw[3][j], false, false);
                o[t][2*st  ][j]     = r[0];
                o[t][2*st  ][j + 2] = r[1];
                o[t][2*st+1][j]     = s[0];
                o[t][2*st+1][j + 2] = s[1];
            }
            PIN_A(o[t][2*st  ]);     // park the finished frags in AGPR
            PIN_A(o[t][2*st+1]);
        }
        __syncthreads();   // live fully consumed by all waves; idle loads drained
    }
}

__launch_bounds__(256, 1)
__global__ void nerf_fused(
    const float* __restrict__ origins, const float* __restrict__ dirs,
    const float* __restrict__ W1, const float* __restrict__ b1,
    const float* __restrict__ b2, const float* __restrict__ b3,
    const float* __restrict__ b4,
    const unsigned* __restrict__ nearp, const unsigned* __restrict__ farp,
    const unsigned short* __restrict__ W2p_, const unsigned short* __restrict__ W3p_,
    const unsigned short* __restrict__ W4p_,
    float* __restrict__ out)
{
    __shared__ char wlds[32768];                // 2 x 16KB weight double-buffer
    const int tid  = threadIdx.x;
    const int w    = tid >> 6;                  // wave = ray-in-block
    const int l    = tid & 63;
    const int hi   = l >> 5;
    const long ray = (long)blockIdx.x * 4 + w;
    const char* W2p = (const char*)W2p_;
    const char* W3p = (const char*)W3p_;
    const char* W4p = (const char*)W4p_;

    const float nearv = decode_scalar(nearp);
    const float farv  = decode_scalar(farp);
    const float delta = (farv - nearv) * (1.0f / 64.0f);

    // prologue: async-stage W2 tile0 -> buf0 (latency hides under layer 1)
#pragma unroll
    for (int j = 0; j < 4; ++j)
        gload_lds16(W2p + j * 4096 + tid * 16, wlds + j * 4096 + tid * 16);

    // ---- layer 1: h1 = relu((o@W1+b1) + z*(d@W1)); fp32, packed straight to regs.
    // owdw scratch in buf1 (wave slice; consumed before st0's async loads hit buf1).
    float* owdw = (float*)(wlds + 16384) + w * 512;
    {
        float o0 = origins[ray*3+0], o1 = origins[ray*3+1], o2 = origins[ray*3+2];
        float d0 = dirs[ray*3+0],    d1 = dirs[ray*3+1],    d2 = dirs[ray*3+2];
        int n0 = l * 4;
        f32x4 wa = *(const f32x4*)(W1 + n0);
        f32x4 wb = *(const f32x4*)(W1 + 256 + n0);
        f32x4 wc = *(const f32x4*)(W1 + 512 + n0);
        f32x4 bbv = *(const f32x4*)(b1 + n0);
        f32x4 ow, dw;
#pragma unroll
        for (int e = 0; e < 4; ++e) {
            ow[e] = fmaf(o2, wc[e], fmaf(o1, wb[e], fmaf(o0, wa[e], bbv[e])));
            dw[e] = fmaf(d2, wc[e], fmaf(d1, wb[e], d0 * wa[e]));
        }
        *(f32x4*)(owdw + n0) = ow;
        *(f32x4*)(owdw + 256 + n0) = dw;
    }
    i32x4 hf[2][16], hg[2][16];
    {
        float s0 = (float)(l & 31);
        float z0 = nearv + (farv - nearv) * (s0 + 0.5f)  * 0.015625f;
        float z1 = nearv + (farv - nearv) * (s0 + 32.5f) * 0.015625f;
#pragma unroll
        for (int kt = 0; kt < 16; ++kt) {
            int k0 = kt * 16 + 8 * hi;
            f32x4 oa = *(const f32x4*)(owdw + k0);
            f32x4 ob = *(const f32x4*)(owdw + k0 + 4);
            f32x4 da = *(const f32x4*)(owdw + 256 + k0);
            f32x4 db = *(const f32x4*)(owdw + 256 + k0 + 4);
#pragma unroll
            for (int t = 0; t < 2; ++t) {
                float z = t ? z1 : z0;
                i32x4 pk;
                pk[0] = (int)cvt_pk_bf16(fmaxf(fmaf(z,da[0],oa[0]),0.f), fmaxf(fmaf(z,da[1],oa[1]),0.f));
                pk[1] = (int)cvt_pk_bf16(fmaxf(fmaf(z,da[2],oa[2]),0.f), fmaxf(fmaf(z,da[3],oa[3]),0.f));
                pk[2] = (int)cvt_pk_bf16(fmaxf(fmaf(z,db[0],ob[0]),0.f), fmaxf(fmaf(z,db[1],ob[1]),0.f));
                pk[3] = (int)cvt_pk_bf16(fmaxf(fmaf(z,db[2],ob[2]),0.f), fmaxf(fmaf(z,db[3],ob[3]),0.f));
                hf[t][kt] = pk;
                PIN_A(hf[t][kt]);          // park layer-1 h in AGPR
            }
        }
    }
    __syncthreads();   // buf0 staged (vmcnt drained by barrier); owdw consumed

    // ---- layers 2, 3 (17-tile async chain: W2 x8 -> W3 x8 -> W4) ----
    dense_layer<0>(hf, hg, wlds, W2p, W3p, W4p, b2, tid, l, hi);
    dense_layer<8>(hg, hf, wlds, W2p, W3p, W4p, b3, tid, l, hi);
    // W4 fragments now in buf0 (gi=16 even)

    // ---- layer 4: 256 -> 4 (padded to 32 rows) + sigmoid/alpha ----
    float* comp = (float*)(wlds + 16384);       // buf1 dead after last barrier
    {
        f32x16 a0 = {}, a1 = {};
#pragma unroll
        for (int kk = 0; kk < 16; ++kk) {
            bf16x8 wv = *(const bf16x8*)(wlds + kk * 1024 + l * 16);
            a0 = __builtin_amdgcn_mfma_f32_32x32x16_bf16(wv, (bf16x8&)hf[0][kk], a0, 0, 0, 0);
            a1 = __builtin_amdgcn_mfma_f32_32x32x16_bf16(wv, (bf16x8&)hf[1][kk], a1, 0, 0, 0);
        }
        // rows 0..3 (r,g,b,sigma) live in regs 0..3 of hi=0 lanes; col = sample&31
        if (l < 32) {
            float bb0 = b4[0], bb1 = b4[1], bb2 = b4[2], bb3 = b4[3];
#pragma unroll
            for (int t = 0; t < 2; ++t) {
                float rr = (t ? a1 : a0)[0] + bb0;
                float gg = (t ? a1 : a0)[1] + bb1;
                float bl = (t ? a1 : a0)[2] + bb2;
                float sg = (t ? a1 : a0)[3] + bb3;
                float alpha = 1.0f - __expf(-fmaxf(sg, 0.0f) * delta);
                f32x4 cv;
                cv[0] = 1.0f / (1.0f + __expf(-rr));
                cv[1] = 1.0f / (1.0f + __expf(-gg));
                cv[2] = 1.0f / (1.0f + __expf(-bl));
                cv[3] = alpha;
                *(f32x4*)(comp + (w * 64 + t * 32 + l) * 4) = cv;   // wave-private
            }
        }
        asm volatile("s_waitcnt lgkmcnt(0)" ::: "memory");  // same-wave write->read
    }

    // ---- composite: each wave scans its own ray; sample = lane ----
    {
        f32x4 cv = *(const f32x4*)(comp + (w * 64 + l) * 4);
        float alpha = cv[3];
        float p = 1.0f - alpha + 1e-10f;
        float P = p;                         // inclusive cumprod across 64 lanes
#pragma unroll
        for (int d = 1; d < 64; d <<= 1) {
            float u = __shfl_up(P, d, 64);
            if (l >= d) P *= u;
        }
        float T = __shfl_up(P, 1, 64);       // exclusive
        if (l == 0) T = 1.0f;
        float wt = alpha * T;
        float cr = wt * cv[0], cg = wt * cv[1], cb = wt * cv[2];
#pragma unroll
        for (int d = 32; d >= 1; d >>= 1) {
            cr += __shfl_down(cr, d, 64);
            cg += __shfl_down(cg, d, 64);
            cb += __shfl_down(cb, d, 64);
        }
        if (l == 0) {
            out[ray * 3 + 0] = cr;
            out[ray * 3 + 1] = cg;
            out[ray * 3 + 2] = cb;
        }
    }
}

extern "C" void kernel_launch(void* const* d_in, const int* in_sizes, int n_in,
                              void* d_out, int out_size, void* d_ws, size_t ws_size,
                              hipStream_t stream) {
    const float* origins = (const float*)d_in[0];
    const float* dirs    = (const float*)d_in[1];
    const float* W1 = (const float*)d_in[2];
    const float* b1 = (const float*)d_in[3];
    const float* W2 = (const float*)d_in[4];
    const float* b2 = (const float*)d_in[5];
    const float* W3 = (const float*)d_in[6];
    const float* b3 = (const float*)d_in[7];
    const float* W4 = (const float*)d_in[8];
    const float* b4 = (const float*)d_in[9];
    const unsigned* nearp = (const unsigned*)d_in[10];
    const unsigned* farp  = (const unsigned*)d_in[11];
    float* out = (float*)d_out;

    unsigned short* W2p = (unsigned short*)d_ws;          // 128KB
    unsigned short* W3p = W2p + 65536;                    // 128KB
    unsigned short* W4p = W2p + 131072;                   // 16KB

    prep_pack<<<288, 256, 0, stream>>>(W2, W3, W4, W2p, W3p, W4p);
    nerf_fused<<<4096, 256, 0, stream>>>(origins, dirs, W1, b1, b2, b3, b4,
                                         nearp, farp, W2p, W3p, W4p, out);
}